// Round 8
// baseline (503.056 us; speedup 1.0000x reference)
//
#include <hip/hip_runtime.h>

// AttentionHead: B=8, S1=S2=2048, E=P=1024. Inputs fp32, output fp32.
// Round 11: compose measured-best of every phase.
//   - convert_all single dispatch (round 7, ~56 us)
//   - merged z=3 projection, rmap2 (rounds 4/7, 131-134 us)
//   - scores/out XCD patches REVERTED to round-3-measured 8x1 / 4x1
//     (scores 110 us, out 125 us). Round-5's 2-D patch theory had an
//     arithmetic bug (qb/kb are 33.5 MB not 16.7): FETCH model is
//     A*(gx/pw)+B*(gy/ph) -> 2x4 gives 201 MB > 8x1's measured 151.7.
//     XCD-mapping axis is now FROZEN at measured-best.

typedef unsigned short u16;
typedef __bf16 bf16x8 __attribute__((ext_vector_type(8)));
typedef float f32x4 __attribute__((ext_vector_type(4)));

__device__ __forceinline__ float b2f(u16 u) {
    union { unsigned i; float f; } x; x.i = ((unsigned)u) << 16; return x.f;
}
__device__ __forceinline__ u16 f2b(float f) {
    union { float f; unsigned i; } x; x.f = f;
    unsigned r = x.i + 0x7FFFu + ((x.i >> 16) & 1u);
    return (u16)(r >> 16);
}

// one launch converts q,k,v,W,bias (segmented grid; 8 fp32 -> 8 bf16/thread)
__global__ __launch_bounds__(256)
void convert_all(const float* __restrict__ q, const float* __restrict__ k,
                 const float* __restrict__ v, const float* __restrict__ W,
                 const float* __restrict__ bias,
                 u16* __restrict__ xq, u16* __restrict__ xk,
                 u16* __restrict__ xv, u16* __restrict__ Wc,
                 u16* __restrict__ bc)
{
    const long b = blockIdx.x;
    const float* src; u16* dst; long off; long n;
    if (b < 8192)       { src = q;    dst = xq; off = b;         n = 16777216L; }
    else if (b < 16384) { src = k;    dst = xk; off = b - 8192;  n = 16777216L; }
    else if (b < 24576) { src = v;    dst = xv; off = b - 16384; n = 16777216L; }
    else if (b < 25088) { src = W;    dst = Wc; off = b - 24576; n = 1048576L;  }
    else                { src = bias; dst = bc; off = 0;         n = 1024L;     }
    const long i = (off * 256 + threadIdx.x) * 8;
    if (i >= n) return;
    const float4* s = (const float4*)(src + i);
    float4 a = s[0], c = s[1];
    ushort4 lo, hi;
    lo.x = f2b(a.x); lo.y = f2b(a.y); lo.z = f2b(a.z); lo.w = f2b(a.w);
    hi.x = f2b(c.x); hi.y = f2b(c.y); hi.z = f2b(c.z); hi.w = f2b(c.w);
    *(ushort4*)(dst + i) = lo;
    *(ushort4*)(dst + i + 4) = hi;
}

// ---------------------------------------------------------------------------
// 256x256 8-phase GEMM: C = alpha*(A B^T) + bias. A:(M,K) lda=K bf16;
// B:(N,K) ldb=K bf16. 512 threads = 8 waves (2M x 4N), per-wave 128x64 out.
// BK=64, 2 K-tiles/iter, 2-buffer 128 KiB LDS, one half-tile stage per
// phase, counted vmcnt(4) at phases 4/8 only (ledger in round-7 journal).
// em 0: bf16 C (+bias,alpha). em 1: fp32 C. em 2: transposed vT bf16 store.
// em 5: merged proj: A = {A0,A1,A2}[z]; z<2 -> em0 bf16 C; z==2 -> em2.
// rmap 2 (proj, grid 4x64x3): g=x+y*4+z*256; xcd=g&7; i=g>>3;
//         G=xcd*24+(i>>2); tx=i&3; z'=G>>6; ty=G&63  (bijective over 768;
//         the 4 blocks sharing an A-panel land on one XCD).
// rmap 3 (patch, z untouched): lin=ty*gx+tx; xcd=lin&7; i=lin>>3;
//         pcols=gx/pw; pr=xcd/pcols; pc=xcd-pr*pcols;
//         tx=pc*pw+i%pw; ty=pr*ph+i/pw.
//   MEASURED-BEST (round 3): scores pw=8,ph=1 (XCD j owns M-row j: hot
//   512KB A-panel resident, kb streamed; 110 us, FETCH 151.7);
//   out pw=4,ph=1 (125 us). 2-D patches measured worse — do not revisit.
// LDS swizzle (conflicts=0): LDS(row, chunk c) holds global chunk (c^(row&7)),
// staged via pre-swizzled global source, linear LDS dest.
// ---------------------------------------------------------------------------

#define BARX()   __builtin_amdgcn_s_barrier()
#define WAITL0() asm volatile("s_waitcnt lgkmcnt(0)" ::: "memory")
#define WV4()    asm volatile("s_waitcnt vmcnt(4)" ::: "memory")
#define WV0()    asm volatile("s_waitcnt vmcnt(0)" ::: "memory")
#define PRIO1()  __builtin_amdgcn_s_setprio(1)
#define PRIO0()  __builtin_amdgcn_s_setprio(0)

__global__ __launch_bounds__(512, 2)
void gemm8(const u16* __restrict__ A0, const u16* __restrict__ A1,
           const u16* __restrict__ A2, const u16* __restrict__ B,
           void* __restrict__ C, const u16* __restrict__ bias,
           int K, float alpha, int em, int ldc,
           long zA, long zB, long zC, int rmap, int pw, int ph)
{
    __shared__ __align__(16) u16 lds[65536];   // 128 KB: [2 buf][A|B][256][64]

    int tx = blockIdx.x, ty = blockIdx.y, z = blockIdx.z;
    if (rmap == 2) {
        const int g = tx + ty * 4 + z * 256;
        const int xcd = g & 7, i = g >> 3;
        const int G = xcd * 24 + (i >> 2);
        tx = i & 3; z = G >> 6; ty = G & 63;
    } else if (rmap == 3) {
        const int gx = gridDim.x;
        const int lin = ty * gx + tx;
        const int xcd = lin & 7, i = lin >> 3;
        const int pcols = gx / pw;
        const int pr = xcd / pcols, pc = xcd - pr * pcols;
        tx = pc * pw + (i % pw);
        ty = pr * ph + (i / pw);
    }

    const int eff5 = (em == 5);
    const u16* Ap = eff5 ? (z == 0 ? A0 : (z == 1 ? A1 : A2)) : A0 + zA * z;
    const u16* Bp = B + zB * z;
    const long coff = zC * z;
    const int eme = eff5 ? (z == 2 ? 2 : 0) : em;

    const int bm0 = ty << 8, bn0 = tx << 8;

    const int tid = threadIdx.x;
    const int wave = tid >> 6, lane = tid & 63;
    const int wm = wave >> 2, wn = wave & 3;       // 2 x 4 wave grid
    const int quad = lane >> 4, l15 = lane & 15;
    const int sw = l15 & 7;

    // staging geometry: LDS dest linear (base + lane*16B); global source
    // column pre-swizzled (both-sides-or-neither rule).
    const int srow = (wave << 3) + (lane >> 3);          // 0..63 in q-block
    const int sgc  = (((lane & 7) ^ (lane >> 3)) << 3);  // swizzled col (elems)
    const int sdst = (wave << 9) + (lane << 3);          // u16 in q-block

#define STG_A(b, h, kt) do {                                                          \
    _Pragma("unroll")                                                                 \
    for (int q_ = 0; q_ < 2; ++q_)                                                    \
        __builtin_amdgcn_global_load_lds(                                             \
            (const __attribute__((address_space(1))) void*)(                          \
                Ap + (long)(bm0 + (h)*128 + q_*64 + srow) * K + (kt) + sgc),          \
            (__attribute__((address_space(3))) void*)(                                \
                lds + (b)*32768 + ((h)*128 + q_*64)*64 + sdst),                       \
            16, 0, 0);                                                                \
} while (0)

#define STG_B(b, h, kt) do {                                                          \
    _Pragma("unroll")                                                                 \
    for (int q_ = 0; q_ < 2; ++q_)                                                    \
        __builtin_amdgcn_global_load_lds(                                             \
            (const __attribute__((address_space(1))) void*)(                          \
                Bp + (long)(bn0 + (h)*128 + q_*64 + srow) * K + (kt) + sgc),          \
            (__attribute__((address_space(3))) void*)(                                \
                lds + (b)*32768 + 16384 + ((h)*128 + q_*64)*64 + sdst),               \
            16, 0, 0);                                                                \
} while (0)

#define LDA(b, m, kk) (*(const bf16x8*)(lds + (b)*32768 +                             \
    ((wm << 7) + ((m) << 4) + l15) * 64 + (((((kk) << 2) + quad) ^ sw) << 3)))
#define LDB(b, n, kk) (*(const bf16x8*)(lds + (b)*32768 + 16384 +                     \
    ((wn << 6) + ((n) << 4) + l15) * 64 + (((((kk) << 2) + quad) ^ sw) << 3)))

#define RD_A(b, mh) do {                                                              \
    _Pragma("unroll") for (int mr = 0; mr < 4; ++mr)                                  \
    _Pragma("unroll") for (int kk = 0; kk < 2; ++kk)                                  \
        af[mr][kk] = LDA(b, (mh)*4 + mr, kk);                                         \
} while (0)
#define RD_B(b, nh) do {                                                              \
    _Pragma("unroll") for (int j = 0; j < 2; ++j)                                     \
    _Pragma("unroll") for (int kk = 0; kk < 2; ++kk)                                  \
        bq[nh][j][kk] = LDB(b, (nh)*2 + j, kk);                                       \
} while (0)

#define MMAQ(mh, nh) do {                                                             \
    _Pragma("unroll") for (int mr = 0; mr < 4; ++mr)                                  \
    _Pragma("unroll") for (int j = 0; j < 2; ++j)                                     \
    _Pragma("unroll") for (int kk = 0; kk < 2; ++kk)                                  \
        acc[(mh)*4 + mr][(nh)*2 + j] = __builtin_amdgcn_mfma_f32_16x16x32_bf16(       \
            af[mr][kk], bq[nh][j][kk], acc[(mh)*4 + mr][(nh)*2 + j], 0, 0, 0);        \
} while (0)

    f32x4 acc[8][4];
#pragma unroll
    for (int m = 0; m < 8; ++m)
#pragma unroll
        for (int n = 0; n < 4; ++n) acc[m][n] = f32x4{0.f, 0.f, 0.f, 0.f};

    bf16x8 af[4][2];        // current mh quadrant fragments
    bf16x8 bq[2][2][2];     // both nh halves, live across the 4 phases

    // prologue: tile0 -> buf0 (all 4 halves), tile1 B-halves -> buf1.
    STG_B(0, 0, 0); STG_B(0, 1, 0);
    STG_A(0, 0, 0); STG_A(0, 1, 0);
    STG_B(1, 0, 64); STG_B(1, 1, 64);
    WV4(); BARX();

    const int NI = K >> 7;                 // 128 K-cols (2 tiles) per iter
    for (int i = 0; i < NI - 1; ++i) {
        const int kt0 = i << 7;
        const int kt1 = kt0 + 64, kt2 = kt0 + 128, kt3 = kt0 + 192;
        // P0
        RD_A(0, 0); RD_B(0, 0); STG_A(1, 0, kt1);
        BARX(); WAITL0(); PRIO1(); MMAQ(0, 0); PRIO0(); BARX();
        // P1
        RD_B(0, 1); STG_A(1, 1, kt1);
        BARX(); WAITL0(); PRIO1(); MMAQ(0, 1); PRIO0(); BARX();
        // P2
        RD_A(0, 1); STG_B(0, 0, kt2);
        BARX(); WAITL0(); PRIO1(); MMAQ(1, 0); PRIO0(); BARX();
        // P3 (K-tile boundary: counted wait, never 0)
        STG_B(0, 1, kt2);
        BARX(); PRIO1(); MMAQ(1, 1); PRIO0(); WV4(); BARX();
        // P4
        RD_A(1, 0); RD_B(1, 0); STG_A(0, 0, kt2);
        BARX(); WAITL0(); PRIO1(); MMAQ(0, 0); PRIO0(); BARX();
        // P5
        RD_B(1, 1); STG_A(0, 1, kt2);
        BARX(); WAITL0(); PRIO1(); MMAQ(0, 1); PRIO0(); BARX();
        // P6
        RD_A(1, 1); STG_B(1, 0, kt3);
        BARX(); WAITL0(); PRIO1(); MMAQ(1, 0); PRIO0(); BARX();
        // P7 (K-tile boundary)
        STG_B(1, 1, kt3);
        BARX(); PRIO1(); MMAQ(1, 1); PRIO0(); WV4(); BARX();
    }
    {   // final iteration: tiles 2NI-2 (buf0), 2NI-1 (buf1); only buf1.A staged
        const int kt1 = ((NI - 1) << 7) + 64;
        RD_A(0, 0); RD_B(0, 0); STG_A(1, 0, kt1);
        BARX(); WAITL0(); PRIO1(); MMAQ(0, 0); PRIO0(); BARX();
        RD_B(0, 1); STG_A(1, 1, kt1);
        BARX(); WAITL0(); PRIO1(); MMAQ(0, 1); PRIO0(); BARX();
        RD_A(0, 1);
        BARX(); WAITL0(); PRIO1(); MMAQ(1, 0); PRIO0(); BARX();
        PRIO1(); MMAQ(1, 1); PRIO0(); WV0(); BARX();   // drain: buf1.A landed
        RD_A(1, 0); RD_B(1, 0);
        BARX(); WAITL0(); PRIO1(); MMAQ(0, 0); PRIO0(); BARX();
        RD_B(1, 1);
        BARX(); WAITL0(); PRIO1(); MMAQ(0, 1); PRIO0(); BARX();
        RD_A(1, 1);
        BARX(); WAITL0(); PRIO1(); MMAQ(1, 0); PRIO0(); BARX();
        PRIO1(); MMAQ(1, 1); PRIO0();
    }

    // epilogue; C/D layout: col = lane&15, row = quad*4 + reg (m89/m91)
#pragma unroll
    for (int m = 0; m < 8; ++m) {
        const int row = bm0 + (wm << 7) + (m << 4) + (quad << 2);
#pragma unroll
        for (int n = 0; n < 4; ++n) {
            const int col = bn0 + (wn << 6) + (n << 4) + l15;
            const float bv = bias ? b2f(bias[col]) : 0.f;
            f32x4 v = acc[m][n];
            const float o0 = alpha * v[0] + bv;
            const float o1 = alpha * v[1] + bv;
            const float o2 = alpha * v[2] + bv;
            const float o3 = alpha * v[3] + bv;
            if (eme == 2) {
                ushort4 pk;
                pk.x = f2b(o0); pk.y = f2b(o1); pk.z = f2b(o2); pk.w = f2b(o3);
                *(ushort4*)((u16*)C + coff + ((long)(row >> 11) << 21)
                            + ((long)col << 11) + (row & 2047)) = pk;
            } else if (eme == 1) {
                float* Cf = (float*)C + coff;
                Cf[(long)(row + 0) * ldc + col] = o0;
                Cf[(long)(row + 1) * ldc + col] = o1;
                Cf[(long)(row + 2) * ldc + col] = o2;
                Cf[(long)(row + 3) * ldc + col] = o3;
            } else {
                u16* Cb = (u16*)C + coff;
                Cb[(long)(row + 0) * ldc + col] = f2b(o0);
                Cb[(long)(row + 1) * ldc + col] = f2b(o1);
                Cb[(long)(row + 2) * ldc + col] = f2b(o2);
                Cb[(long)(row + 3) * ldc + col] = f2b(o3);
            }
        }
    }
}

// in-place softmax over rows of 2048 bf16; one block (256 thr) per row
__global__ __launch_bounds__(256)
void softmax_rows(u16* __restrict__ S)
{
    const long row = blockIdx.x;
    u16* p = S + (row << 11);
    const int tid = threadIdx.x, wave = tid >> 6, lane = tid & 63;

    union { uint4 q; u16 u[8]; } d;
    d.q = ((const uint4*)p)[tid];
    float v[8];
#pragma unroll
    for (int i = 0; i < 8; i++) v[i] = b2f(d.u[i]);

    float m = v[0];
#pragma unroll
    for (int i = 1; i < 8; i++) m = fmaxf(m, v[i]);
#pragma unroll
    for (int o = 32; o; o >>= 1) m = fmaxf(m, __shfl_xor(m, o, 64));
    __shared__ float redm[4], reds[4];
    if (lane == 0) redm[wave] = m;
    __syncthreads();
    m = fmaxf(fmaxf(redm[0], redm[1]), fmaxf(redm[2], redm[3]));

    float e[8], s = 0.f;
#pragma unroll
    for (int i = 0; i < 8; i++) { e[i] = __expf(v[i] - m); s += e[i]; }
#pragma unroll
    for (int o = 32; o; o >>= 1) s += __shfl_xor(s, o, 64);
    if (lane == 0) reds[wave] = s;
    __syncthreads();
    s = reds[0] + reds[1] + reds[2] + reds[3];

    const float inv = 1.f / s;
#pragma unroll
    for (int i = 0; i < 8; i++) d.u[i] = f2b(e[i] * inv);
    ((uint4*)p)[tid] = d.q;
}

extern "C" void kernel_launch(void* const* d_in, const int* in_sizes, int n_in,
                              void* d_out, int out_size, void* d_ws, size_t ws_size,
                              hipStream_t stream) {
    const float* query = (const float*)d_in[0];   // (8,2048,1024) fp32
    const float* key   = (const float*)d_in[1];
    const float* value = (const float*)d_in[2];
    const float* W     = (const float*)d_in[3];   // (1024,1024) fp32 (P,E)
    const float* bias  = (const float*)d_in[4];   // (1024,) fp32
    float* out = (float*)d_out;                   // (8,2048,1024) fp32

    // ws (u16 elems), 167.8 MB:
    //   [0, 33.5M)    sc (scores) | aliased early: xq @0, xk @16.7M
    //   [33.5M..)     qb | kb | vT  (3 x 16.7M)
    // d_out (u16 view), dead until final GEMM:
    //   xv @0 (16.7M), Wc @16.7M (1.05M), bc after
    // Timeline: conv(q,k,v,W,b) -> proj(reads xq,xk,xv,Wc; writes qb,kb,vT)
    //   -> scores(reads qb,kb; writes sc) -> softmax(sc)
    //   -> out(reads sc,vT; writes d_out). No alias window.
    u16* sc  = (u16*)d_ws;
    u16* xq  = (u16*)d_ws;
    u16* xk  = (u16*)d_ws + 16777216L;
    u16* qb  = (u16*)d_ws + 33554432L;
    u16* kb  = qb + 16777216L;
    u16* vT  = kb + 16777216L;
    u16* xv  = (u16*)d_out;
    u16* Wc  = (u16*)d_out + 16777216L;
    u16* bc  = Wc + 1048576L;

    const dim3 blk2(256), blk5(512);

    // one launch: q,k,v (8192 blocks each), W (512), bias (1)
    convert_all<<<dim3(25089), blk2, 0, stream>>>(query, key, value, W, bias,
                                                  xq, xk, xv, Wc, bc);

    // merged projections: per z: M=16384, N=1024, K=1024. 768 blocks,
    // group-per-XCD remap (rmap 2). z<2 bf16 C; z==2 transposed vT.
    gemm8<<<dim3(4, 64, 3), blk5, 0, stream>>>(xq, xk, xv, Wc, qb, bc,
        1024, 1.f, 5, 1024, 0, 0, 16777216L, 2, 0, 0);

    // scores: per batch M=N=2048, K=1024, alpha=1/32; measured-best 8x1 patch
    gemm8<<<dim3(8, 8, 8), blk5, 0, stream>>>(qb, nullptr, nullptr, kb, sc, nullptr,
        1024, 0.03125f, 0, 2048, 2048L * 1024, 2048L * 1024, 2048L * 2048, 3, 8, 1);

    // softmax rows (8*2048), in place
    softmax_rows<<<dim3(16384), blk2, 0, stream>>>(sc);

    // out = S @ vT^T: per batch M=2048, N=1024, K=2048, fp32 C; 4x1 patch
    gemm8<<<dim3(4, 8, 8), blk5, 0, stream>>>(sc, nullptr, nullptr, vT, out, nullptr,
        2048, 1.f, 1, 1024, 2048L * 2048, 1024L * 2048, 2048L * 1024, 3, 4, 1);
}

// Round 9
// 487.865 us; speedup vs baseline: 1.0311x; 1.0311x over previous
//
#include <hip/hip_runtime.h>

// AttentionHead: B=8, S1=S2=2048, E=P=1024. Inputs fp32, output fp32.
// Round 12: triple-buffered A / double-buffered B (160 KB LDS, AITER-
// precedented). The frozen core's WV4 forced buf1.A landed 2.5 phases
// after issue (~450 cy < 900 cy HBM latency) -> ~2x stall per K-boundary.
// New ledger: P0/P1 stage A(u+2), P4/P5 stage A(u+3) (3-buf rotation),
// B unchanged; WV8 at P3/P7 retires exactly one full tile; min slack now
// 5 phases (~1300 cy) > HBM latency. Phase structure, swizzle, epilogue,
// rmaps, launches byte-identical to round 8 (one variable).

typedef unsigned short u16;
typedef __bf16 bf16x8 __attribute__((ext_vector_type(8)));
typedef float f32x4 __attribute__((ext_vector_type(4)));

__device__ __forceinline__ float b2f(u16 u) {
    union { unsigned i; float f; } x; x.i = ((unsigned)u) << 16; return x.f;
}
__device__ __forceinline__ u16 f2b(float f) {
    union { float f; unsigned i; } x; x.f = f;
    unsigned r = x.i + 0x7FFFu + ((x.i >> 16) & 1u);
    return (u16)(r >> 16);
}

// one launch converts q,k,v,W,bias (segmented grid; 8 fp32 -> 8 bf16/thread)
__global__ __launch_bounds__(256)
void convert_all(const float* __restrict__ q, const float* __restrict__ k,
                 const float* __restrict__ v, const float* __restrict__ W,
                 const float* __restrict__ bias,
                 u16* __restrict__ xq, u16* __restrict__ xk,
                 u16* __restrict__ xv, u16* __restrict__ Wc,
                 u16* __restrict__ bc)
{
    const long b = blockIdx.x;
    const float* src; u16* dst; long off; long n;
    if (b < 8192)       { src = q;    dst = xq; off = b;         n = 16777216L; }
    else if (b < 16384) { src = k;    dst = xk; off = b - 8192;  n = 16777216L; }
    else if (b < 24576) { src = v;    dst = xv; off = b - 16384; n = 16777216L; }
    else if (b < 25088) { src = W;    dst = Wc; off = b - 24576; n = 1048576L;  }
    else                { src = bias; dst = bc; off = 0;         n = 1024L;     }
    const long i = (off * 256 + threadIdx.x) * 8;
    if (i >= n) return;
    const float4* s = (const float4*)(src + i);
    float4 a = s[0], c = s[1];
    ushort4 lo, hi;
    lo.x = f2b(a.x); lo.y = f2b(a.y); lo.z = f2b(a.z); lo.w = f2b(a.w);
    hi.x = f2b(c.x); hi.y = f2b(c.y); hi.z = f2b(c.z); hi.w = f2b(c.w);
    *(ushort4*)(dst + i) = lo;
    *(ushort4*)(dst + i + 4) = hi;
}

// ---------------------------------------------------------------------------
// 256x256 8-phase GEMM: C = alpha*(A B^T) + bias. A:(M,K) lda=K bf16;
// B:(N,K) ldb=K bf16. 512 threads = 8 waves (2M x 4N), per-wave 128x64 out.
// BK=64, 2 K-tiles (u, u+1) per iteration.
// LDS 160 KB: A bufs {0,16384,32768} (tile t -> buf t%3), B bufs
// {49152, 65536} (tile t -> buf t&1; u=2i so first tile always bbuf0).
// Stage slots (iter i, u=2i): P0/P1: A(u+2)->a2; P2/P3: B(u+2)->bbuf0;
//   P4/P5: A(u+3)->a0 (tile u's A-reads done at P2); P6/P7: B(u+3)->bbuf1.
// Waits: WV8 at P3 (retires A(u+1)+B(u+1)... steady: retires the 8 oldest
//   = tile needed at P4) and WV8 at P7 (retires tile u+2 for next-P0).
//   Min stage->force slack = 5 phases (~1300 cy) > 900 cy HBM latency.
// em 0: bf16 C (+bias,alpha). em 1: fp32 C. em 2: transposed vT bf16 store.
// em 5: merged proj: A = {A0,A1,A2}[z]; z<2 -> em0 bf16 C; z==2 -> em2.
// rmap 2 (proj): bijective over 768; 4 blocks/A-panel per XCD.
// rmap 3 (patch): measured-best scores 8x1 / out 4x1 (round 3). FROZEN.
// LDS swizzle (conflicts=0): LDS(row, chunk c) holds global chunk (c^(row&7)),
// staged via pre-swizzled global source, linear LDS dest.
// ---------------------------------------------------------------------------

#define BARX()   __builtin_amdgcn_s_barrier()
#define WAITL0() asm volatile("s_waitcnt lgkmcnt(0)" ::: "memory")
#define WV8()    asm volatile("s_waitcnt vmcnt(8)" ::: "memory")
#define WV0()    asm volatile("s_waitcnt vmcnt(0)" ::: "memory")
#define PRIO1()  __builtin_amdgcn_s_setprio(1)
#define PRIO0()  __builtin_amdgcn_s_setprio(0)

__global__ __launch_bounds__(512, 2)
void gemm8(const u16* __restrict__ A0, const u16* __restrict__ A1,
           const u16* __restrict__ A2, const u16* __restrict__ B,
           void* __restrict__ C, const u16* __restrict__ bias,
           int K, float alpha, int em, int ldc,
           long zA, long zB, long zC, int rmap, int pw, int ph)
{
    __shared__ __align__(16) u16 lds[81920];   // 160 KB: A x3 @0, B x2 @49152

    int tx = blockIdx.x, ty = blockIdx.y, z = blockIdx.z;
    if (rmap == 2) {
        const int g = tx + ty * 4 + z * 256;
        const int xcd = g & 7, i = g >> 3;
        const int G = xcd * 24 + (i >> 2);
        tx = i & 3; z = G >> 6; ty = G & 63;
    } else if (rmap == 3) {
        const int gx = gridDim.x;
        const int lin = ty * gx + tx;
        const int xcd = lin & 7, i = lin >> 3;
        const int pcols = gx / pw;
        const int pr = xcd / pcols, pc = xcd - pr * pcols;
        tx = pc * pw + (i % pw);
        ty = pr * ph + (i / pw);
    }

    const int eff5 = (em == 5);
    const u16* Ap = eff5 ? (z == 0 ? A0 : (z == 1 ? A1 : A2)) : A0 + zA * z;
    const u16* Bp = B + zB * z;
    const long coff = zC * z;
    const int eme = eff5 ? (z == 2 ? 2 : 0) : em;

    const int bm0 = ty << 8, bn0 = tx << 8;

    const int tid = threadIdx.x;
    const int wave = tid >> 6, lane = tid & 63;
    const int wm = wave >> 2, wn = wave & 3;       // 2 x 4 wave grid
    const int quad = lane >> 4, l15 = lane & 15;
    const int sw = l15 & 7;

    // staging geometry: LDS dest linear (base + lane*16B); global source
    // column pre-swizzled (both-sides-or-neither rule).
    const int srow = (wave << 3) + (lane >> 3);          // 0..63 in q-block
    const int sgc  = (((lane & 7) ^ (lane >> 3)) << 3);  // swizzled col (elems)
    const int sdst = (wave << 9) + (lane << 3);          // u16 in q-block

// ab: A-buf base in u16 (0/16384/32768); bb: B-buf index 0/1
#define STG_A(ab, h, kt) do {                                                         \
    _Pragma("unroll")                                                                 \
    for (int q_ = 0; q_ < 2; ++q_)                                                    \
        __builtin_amdgcn_global_load_lds(                                             \
            (const __attribute__((address_space(1))) void*)(                          \
                Ap + (long)(bm0 + (h)*128 + q_*64 + srow) * K + (kt) + sgc),          \
            (__attribute__((address_space(3))) void*)(                                \
                lds + (ab) + ((h)*128 + q_*64)*64 + sdst),                            \
            16, 0, 0);                                                                \
} while (0)

#define STG_B(bb, h, kt) do {                                                         \
    _Pragma("unroll")                                                                 \
    for (int q_ = 0; q_ < 2; ++q_)                                                    \
        __builtin_amdgcn_global_load_lds(                                             \
            (const __attribute__((address_space(1))) void*)(                          \
                Bp + (long)(bn0 + (h)*128 + q_*64 + srow) * K + (kt) + sgc),          \
            (__attribute__((address_space(3))) void*)(                                \
                lds + 49152 + (bb)*16384 + ((h)*128 + q_*64)*64 + sdst),              \
            16, 0, 0);                                                                \
} while (0)

#define LDA(ab, m, kk) (*(const bf16x8*)(lds + (ab) +                                 \
    ((wm << 7) + ((m) << 4) + l15) * 64 + (((((kk) << 2) + quad) ^ sw) << 3)))
#define LDB(bb, n, kk) (*(const bf16x8*)(lds + 49152 + (bb)*16384 +                   \
    ((wn << 6) + ((n) << 4) + l15) * 64 + (((((kk) << 2) + quad) ^ sw) << 3)))

#define RD_A(ab, mh) do {                                                             \
    _Pragma("unroll") for (int mr = 0; mr < 4; ++mr)                                  \
    _Pragma("unroll") for (int kk = 0; kk < 2; ++kk)                                  \
        af[mr][kk] = LDA(ab, (mh)*4 + mr, kk);                                        \
} while (0)
#define RD_B(bb, nh) do {                                                             \
    _Pragma("unroll") for (int j = 0; j < 2; ++j)                                     \
    _Pragma("unroll") for (int kk = 0; kk < 2; ++kk)                                  \
        bq[nh][j][kk] = LDB(bb, (nh)*2 + j, kk);                                      \
} while (0)

#define MMAQ(mh, nh) do {                                                             \
    _Pragma("unroll") for (int mr = 0; mr < 4; ++mr)                                  \
    _Pragma("unroll") for (int j = 0; j < 2; ++j)                                     \
    _Pragma("unroll") for (int kk = 0; kk < 2; ++kk)                                  \
        acc[(mh)*4 + mr][(nh)*2 + j] = __builtin_amdgcn_mfma_f32_16x16x32_bf16(       \
            af[mr][kk], bq[nh][j][kk], acc[(mh)*4 + mr][(nh)*2 + j], 0, 0, 0);        \
} while (0)

    f32x4 acc[8][4];
#pragma unroll
    for (int m = 0; m < 8; ++m)
#pragma unroll
        for (int n = 0; n < 4; ++n) acc[m][n] = f32x4{0.f, 0.f, 0.f, 0.f};

    bf16x8 af[4][2];        // current mh quadrant fragments
    bf16x8 bq[2][2][2];     // both nh halves, live across the 4 phases

    // prologue: tiles 0 and 1 complete (A0->abuf0, B0->bbuf0, A1->abuf1,
    // B1->bbuf1 = 16 loads); WV8 retires the 8 oldest = tile 0.
    STG_A(0, 0, 0);      STG_A(0, 1, 0);
    STG_B(0, 0, 0);      STG_B(0, 1, 0);
    STG_A(16384, 0, 64); STG_A(16384, 1, 64);
    STG_B(1, 0, 64);     STG_B(1, 1, 64);
    WV8(); BARX();

    int a0 = 0, a1 = 16384, a2 = 32768;    // A-buf bases for tiles u, u+1, u+2
    const int NI = K >> 7;                 // 128 K-cols (2 tiles) per iter
    for (int i = 0; i < NI - 1; ++i) {
        const int kt2 = (i << 7) + 128, kt3 = kt2 + 64;
        // P0
        RD_A(a0, 0); RD_B(0, 0); STG_A(a2, 0, kt2);
        BARX(); WAITL0(); PRIO1(); MMAQ(0, 0); PRIO0(); BARX();
        // P1
        RD_B(0, 1); STG_A(a2, 1, kt2);
        BARX(); WAITL0(); PRIO1(); MMAQ(0, 1); PRIO0(); BARX();
        // P2
        RD_A(a0, 1); STG_B(0, 0, kt2);
        BARX(); WAITL0(); PRIO1(); MMAQ(1, 0); PRIO0(); BARX();
        // P3 (counted: retires tile u+1 for P4; keeps 8 newest in flight)
        STG_B(0, 1, kt2);
        BARX(); PRIO1(); MMAQ(1, 1); PRIO0(); WV8(); BARX();
        // P4 (A(u+3) -> a0: tile u's A-reads completed at P2)
        RD_A(a1, 0); RD_B(1, 0); STG_A(a0, 0, kt3);
        BARX(); WAITL0(); PRIO1(); MMAQ(0, 0); PRIO0(); BARX();
        // P5
        RD_B(1, 1); STG_A(a0, 1, kt3);
        BARX(); WAITL0(); PRIO1(); MMAQ(0, 1); PRIO0(); BARX();
        // P6
        RD_A(a1, 1); STG_B(1, 0, kt3);
        BARX(); WAITL0(); PRIO1(); MMAQ(1, 0); PRIO0(); BARX();
        // P7 (counted: retires tile u+2 for next-P0)
        STG_B(1, 1, kt3);
        BARX(); PRIO1(); MMAQ(1, 1); PRIO0(); WV8(); BARX();
        // rotate A bufs: u += 2  ->  (u%3, u+1%3, u+2%3) rotates right
        const int tmp = a2; a2 = a1; a1 = a0; a0 = tmp;
    }
    {   // final iteration: tiles 2NI-2 (a0/bbuf0), 2NI-1 (a1/bbuf1);
        // all loads already issued; only tile 2NI-1's 8 still in flight.
        RD_A(a0, 0); RD_B(0, 0);
        BARX(); WAITL0(); PRIO1(); MMAQ(0, 0); PRIO0(); BARX();
        RD_B(0, 1);
        BARX(); WAITL0(); PRIO1(); MMAQ(0, 1); PRIO0(); BARX();
        RD_A(a0, 1);
        BARX(); WAITL0(); PRIO1(); MMAQ(1, 0); PRIO0(); BARX();
        PRIO1(); MMAQ(1, 1); PRIO0(); WV0(); BARX();   // drain: tile 2NI-1 landed
        RD_A(a1, 0); RD_B(1, 0);
        BARX(); WAITL0(); PRIO1(); MMAQ(0, 0); PRIO0(); BARX();
        RD_B(1, 1);
        BARX(); WAITL0(); PRIO1(); MMAQ(0, 1); PRIO0(); BARX();
        RD_A(a1, 1);
        BARX(); WAITL0(); PRIO1(); MMAQ(1, 0); PRIO0(); BARX();
        PRIO1(); MMAQ(1, 1); PRIO0();
    }

    // epilogue; C/D layout: col = lane&15, row = quad*4 + reg (m89/m91)
#pragma unroll
    for (int m = 0; m < 8; ++m) {
        const int row = bm0 + (wm << 7) + (m << 4) + (quad << 2);
#pragma unroll
        for (int n = 0; n < 4; ++n) {
            const int col = bn0 + (wn << 6) + (n << 4) + l15;
            const float bv = bias ? b2f(bias[col]) : 0.f;
            f32x4 v = acc[m][n];
            const float o0 = alpha * v[0] + bv;
            const float o1 = alpha * v[1] + bv;
            const float o2 = alpha * v[2] + bv;
            const float o3 = alpha * v[3] + bv;
            if (eme == 2) {
                ushort4 pk;
                pk.x = f2b(o0); pk.y = f2b(o1); pk.z = f2b(o2); pk.w = f2b(o3);
                *(ushort4*)((u16*)C + coff + ((long)(row >> 11) << 21)
                            + ((long)col << 11) + (row & 2047)) = pk;
            } else if (eme == 1) {
                float* Cf = (float*)C + coff;
                Cf[(long)(row + 0) * ldc + col] = o0;
                Cf[(long)(row + 1) * ldc + col] = o1;
                Cf[(long)(row + 2) * ldc + col] = o2;
                Cf[(long)(row + 3) * ldc + col] = o3;
            } else {
                u16* Cb = (u16*)C + coff;
                Cb[(long)(row + 0) * ldc + col] = f2b(o0);
                Cb[(long)(row + 1) * ldc + col] = f2b(o1);
                Cb[(long)(row + 2) * ldc + col] = f2b(o2);
                Cb[(long)(row + 3) * ldc + col] = f2b(o3);
            }
        }
    }
}

// in-place softmax over rows of 2048 bf16; one block (256 thr) per row
__global__ __launch_bounds__(256)
void softmax_rows(u16* __restrict__ S)
{
    const long row = blockIdx.x;
    u16* p = S + (row << 11);
    const int tid = threadIdx.x, wave = tid >> 6, lane = tid & 63;

    union { uint4 q; u16 u[8]; } d;
    d.q = ((const uint4*)p)[tid];
    float v[8];
#pragma unroll
    for (int i = 0; i < 8; i++) v[i] = b2f(d.u[i]);

    float m = v[0];
#pragma unroll
    for (int i = 1; i < 8; i++) m = fmaxf(m, v[i]);
#pragma unroll
    for (int o = 32; o; o >>= 1) m = fmaxf(m, __shfl_xor(m, o, 64));
    __shared__ float redm[4], reds[4];
    if (lane == 0) redm[wave] = m;
    __syncthreads();
    m = fmaxf(fmaxf(redm[0], redm[1]), fmaxf(redm[2], redm[3]));

    float e[8], s = 0.f;
#pragma unroll
    for (int i = 0; i < 8; i++) { e[i] = __expf(v[i] - m); s += e[i]; }
#pragma unroll
    for (int o = 32; o; o >>= 1) s += __shfl_xor(s, o, 64);
    if (lane == 0) reds[wave] = s;
    __syncthreads();
    s = reds[0] + reds[1] + reds[2] + reds[3];

    const float inv = 1.f / s;
#pragma unroll
    for (int i = 0; i < 8; i++) d.u[i] = f2b(e[i] * inv);
    ((uint4*)p)[tid] = d.q;
}

extern "C" void kernel_launch(void* const* d_in, const int* in_sizes, int n_in,
                              void* d_out, int out_size, void* d_ws, size_t ws_size,
                              hipStream_t stream) {
    const float* query = (const float*)d_in[0];   // (8,2048,1024) fp32
    const float* key   = (const float*)d_in[1];
    const float* value = (const float*)d_in[2];
    const float* W     = (const float*)d_in[3];   // (1024,1024) fp32 (P,E)
    const float* bias  = (const float*)d_in[4];   // (1024,) fp32
    float* out = (float*)d_out;                   // (8,2048,1024) fp32

    // ws (u16 elems), 167.8 MB:
    //   [0, 33.5M)    sc (scores) | aliased early: xq @0, xk @16.7M
    //   [33.5M..)     qb | kb | vT  (3 x 16.7M)
    // d_out (u16 view), dead until final GEMM:
    //   xv @0 (16.7M), Wc @16.7M (1.05M), bc after
    u16* sc  = (u16*)d_ws;
    u16* xq  = (u16*)d_ws;
    u16* xk  = (u16*)d_ws + 16777216L;
    u16* qb  = (u16*)d_ws + 33554432L;
    u16* kb  = qb + 16777216L;
    u16* vT  = kb + 16777216L;
    u16* xv  = (u16*)d_out;
    u16* Wc  = (u16*)d_out + 16777216L;
    u16* bc  = Wc + 1048576L;

    const dim3 blk2(256), blk5(512);

    // one launch: q,k,v (8192 blocks each), W (512), bias (1)
    convert_all<<<dim3(25089), blk2, 0, stream>>>(query, key, value, W, bias,
                                                  xq, xk, xv, Wc, bc);

    // merged projections: per z: M=16384, N=1024, K=1024. 768 blocks,
    // group-per-XCD remap (rmap 2). z<2 bf16 C; z==2 transposed vT.
    gemm8<<<dim3(4, 64, 3), blk5, 0, stream>>>(xq, xk, xv, Wc, qb, bc,
        1024, 1.f, 5, 1024, 0, 0, 16777216L, 2, 0, 0);

    // scores: per batch M=N=2048, K=1024, alpha=1/32; measured-best 8x1 patch
    gemm8<<<dim3(8, 8, 8), blk5, 0, stream>>>(qb, nullptr, nullptr, kb, sc, nullptr,
        1024, 0.03125f, 0, 2048, 2048L * 1024, 2048L * 1024, 2048L * 2048, 3, 8, 1);

    // softmax rows (8*2048), in place
    softmax_rows<<<dim3(16384), blk2, 0, stream>>>(sc);

    // out = S @ vT^T: per batch M=2048, N=1024, K=2048, fp32 C; 4x1 patch
    gemm8<<<dim3(4, 8, 8), blk5, 0, stream>>>(sc, nullptr, nullptr, vT, out, nullptr,
        2048, 1.f, 1, 1024, 2048L * 2048, 1024L * 2048, 2048L * 1024, 3, 4, 1);
}